// Round 5
// baseline (146.885 us; speedup 1.0000x reference)
//
#include <hip/hip_runtime.h>
#include <math.h>

#define B_ 4
#define N_ 2048
#define C_ 64
#define K_ 32
#define BN_ (B_ * N_)  // 8192

// ws float layout (all regions fully written each launch before read):
// [0]              nll accumulator (zeroed by k_prep, atomicAdd by k_logits)
// [64, 8256)       INVN  per-row 1/||contr_row||  (k_prep)
// [8320, 16512)    SX = emb.x + absc.x  (k_prep)
// [16512, 24704)   SY = emb.y + absc.y  (k_prep)
// [24704, 32896)   MEANS B*K*C, count-divide fused (k_cluster)
// [32896, 34944)   APART 1024 * {sum, cnt} (k_anchor)
#define WS_NLL 0
#define WS_INVN 64
#define WS_SX 8320
#define WS_SY 16512
#define WS_MEANS 24704
#define WS_APART 32896

// 2048 blocks x 256: wave = one contr row (inv-norm); first 8192 flat threads
// also write SX/SY; thread 0 zeroes the nll accumulator.
__global__ __launch_bounds__(256) void k_prep(
    const float* __restrict__ emb, const float* __restrict__ absc,
    const float* __restrict__ contr, float* __restrict__ ws) {
  int t = threadIdx.x, lane = t & 63, w = t >> 6;
  int flat = blockIdx.x * 256 + t;
  if (flat == 0) ws[WS_NLL] = 0.0f;
  if (flat < BN_) {
    float2 ev = ((const float2*)emb)[flat];
    float2 av = ((const float2*)absc)[flat];
    ws[WS_SX + flat] = ev.x + av.x;
    ws[WS_SY + flat] = ev.y + av.y;
  }
  int row = blockIdx.x * 4 + w;
  float x = contr[row * C_ + lane];
  float ss = x * x;
#pragma unroll
  for (int off = 32; off > 0; off >>= 1) ss += __shfl_xor(ss, off);
  if (lane == 0) ws[WS_INVN + row] = 1.0f / fmaxf(sqrtf(ss), 1e-12f);
}

// 128 blocks (one per (batch, cluster)) x 256. Labels staged to LDS once;
// each wave ballot-scans 512 rows (8 ballots); matched rows pulled as
// coalesced 256B wave-loads. Divide fused -> MEANS directly.
__global__ __launch_bounds__(256) void k_cluster(
    const float* __restrict__ contr, const int* __restrict__ labels,
    float* __restrict__ ws) {
  __shared__ int lsLab[N_];        // 8 KB
  __shared__ float lsum[4][64];
  __shared__ float lcnt[4];
  int t = threadIdx.x, lane = t & 63, w = t >> 6;
  int b = blockIdx.x >> 5, k = blockIdx.x & 31;
  const int4* lab4 = (const int4*)(labels + b * N_);
  int4* l4 = (int4*)lsLab;
  l4[t] = lab4[t];
  l4[t + 256] = lab4[t + 256];
  __syncthreads();
  float acc = 0.0f, cnt = 0.0f;
  for (int g0 = w * 512; g0 < w * 512 + 512; g0 += 64) {
    unsigned long long mb = __ballot(lsLab[g0 + lane] == k);
    while (mb) {
      int bit = __ffsll((unsigned long long)mb) - 1;
      mb &= mb - 1;
      int r = b * N_ + g0 + bit;
      float inv = ws[WS_INVN + r];
      acc += contr[(size_t)r * C_ + lane] * inv;
      cnt += 1.0f;
    }
  }
  lsum[w][lane] = acc;
  if (lane == 0) lcnt[w] = cnt;
  __syncthreads();
  if (t < 64) {
    float s = lsum[0][t] + lsum[1][t] + lsum[2][t] + lsum[3][t];
    float c = lcnt[0] + lcnt[1] + lcnt[2] + lcnt[3];
    ws[WS_MEANS + (b * K_ + k) * C_ + t] = s / fmaxf(c, 1.0f);
  }
}

// 256 blocks x 128 (2 waves). Block = 32 rows. lane = logit column
// (wave w -> cols [w*64, w*64+64)). Means in 16 float4 VGPRs; rows stream
// via LDS wave-uniform b128 broadcasts. Softmax + nll fused.
__global__ __launch_bounds__(128) void k_logits_nll(
    const float* __restrict__ contr, const int* __restrict__ labels,
    float* __restrict__ ws) {
  __shared__ float lc[32 * C_];    // 8 KB raw rows
  __shared__ float lm[2][32], lsv[2][32], ltl[32];
  int t = threadIdx.x, lane = t & 63, w = t >> 6;
  int r0 = blockIdx.x * 32;
  int j = w * 64 + lane;
  const float4* mean4 = (const float4*)(ws + WS_MEANS);
  float4 mk[16];
#pragma unroll
  for (int q = 0; q < 16; ++q) mk[q] = mean4[j * 16 + q];
  const float4* c4 = (const float4*)(contr + (size_t)r0 * C_);
  float4* lc4 = (float4*)lc;
  lc4[t] = c4[t];
  lc4[t + 128] = c4[t + 128];
  lc4[t + 256] = c4[t + 256];
  lc4[t + 384] = c4[t + 384];
  __syncthreads();
  for (int r = 0; r < 32; ++r) {
    const float4* cr = lc4 + r * 16;
    float acc = 0.0f;
#pragma unroll
    for (int q = 0; q < 16; ++q) {
      float4 cv = cr[q];
      acc += cv.x * mk[q].x + cv.y * mk[q].y + cv.z * mk[q].z + cv.w * mk[q].w;
    }
    acc *= ws[WS_INVN + r0 + r];
    float m = acc;
#pragma unroll
    for (int off = 32; off > 0; off >>= 1) m = fmaxf(m, __shfl_xor(m, off));
    float s = __expf(acc - m);
#pragma unroll
    for (int off = 32; off > 0; off >>= 1) s += __shfl_xor(s, off);
    int tgt = labels[r0 + r];            // [0,32): wave 0's columns
    float tl = __shfl(acc, tgt);
    if (lane == 0) {
      lm[w][r] = m;
      lsv[w][r] = s;
      if (w == 0) ltl[r] = tl;
    }
  }
  __syncthreads();
  if (t < 32) {
    float m0 = lm[0][t], m1 = lm[1][t];
    float mm = fmaxf(m0, m1);
    float ss = lsv[0][t] * __expf(m0 - mm) + lsv[1][t] * __expf(m1 - mm);
    float nll = (mm + __logf(ss)) - ltl[t];
#pragma unroll
    for (int off = 16; off > 0; off >>= 1) nll += __shfl_xor(nll, off);
    if (t == 0) atomicAdd(&ws[WS_NLL], nll);
  }
}

__device__ __forceinline__ void pair4(float sx, float sy, float4 xs, float4 ys,
                                      int4 m, float& acc, int& cnt) {
  float dx, dy, d2, v;
  dx = sx - xs.x; dy = sy - ys.x; d2 = dx * dx + dy * dy;
  v = 1.0f - __expf(d2 * -0.1f);
  if (m.x == 1) { acc += v; cnt += 1; }
  dx = sx - xs.y; dy = sy - ys.y; d2 = dx * dx + dy * dy;
  v = 1.0f - __expf(d2 * -0.1f);
  if (m.y == 1) { acc += v; cnt += 1; }
  dx = sx - xs.z; dy = sy - ys.z; d2 = dx * dx + dy * dy;
  v = 1.0f - __expf(d2 * -0.1f);
  if (m.z == 1) { acc += v; cnt += 1; }
  dx = sx - xs.w; dy = sy - ys.w; d2 = dx * dx + dy * dy;
  v = 1.0f - __expf(d2 * -0.1f);
  if (m.w == 1) { acc += v; cnt += 1; }
}

// Grid-stride streaming anchor — shape-identical to a memcpy reader, which
// hits 6.3+ TB/s on this machine (R4's fillBuffer @6.45 TB/s). 1024 blocks
// x 256; thread's global-linear int4 index: idx = flat + it*262144, it<16.
//  - column group cg = flat & 511 is ITERATION-INVARIANT -> xs/ys float4
//    loaded once per batch section (4 total);
//  - batch b == it/4 exactly (512-row steps, 4 per batch);
//  - row = idx>>9 is wave-uniform (512 int4 per row, 8 waves per row).
// Per section: 4 independent int4 loads fully unrolled -> continuous stream,
// no LDS, no mid-kernel barrier. Per-block partials, no global atomics.
__global__ __launch_bounds__(256) void k_anchor(
    const int* __restrict__ mask, float* __restrict__ ws) {
  __shared__ float red[8];
  int t = threadIdx.x, lane = t & 63, w = t >> 6;
  int flat = blockIdx.x * 256 + t;       // [0, 262144)
  int cg = flat & 511;                   // fixed float4 column group
  const int4* m4 = (const int4*)mask;
  const float* wsx = ws + WS_SX;
  const float* wsy = ws + WS_SY;
  const float4* sx4 = (const float4*)wsx;
  const float4* sy4 = (const float4*)wsy;
  float acc = 0.0f;
  int cnt = 0;
#pragma unroll
  for (int bt = 0; bt < 4; ++bt) {
    float4 xs = sx4[bt * 512 + cg];
    float4 ys = sy4[bt * 512 + cg];
#pragma unroll
    for (int j = 0; j < 4; ++j) {
      int idx = flat + (bt * 4 + j) * 262144;
      int4 m = m4[idx];
      int row = idx >> 9;                // wave-uniform
      float rx = wsx[row], ry = wsy[row];
      pair4(rx, ry, xs, ys, m, acc, cnt);
    }
  }
  float cntf = (float)cnt;
#pragma unroll
  for (int off = 32; off > 0; off >>= 1) {
    acc += __shfl_xor(acc, off);
    cntf += __shfl_xor(cntf, off);
  }
  if (lane == 0) { red[w * 2] = acc; red[w * 2 + 1] = cntf; }
  __syncthreads();
  if (t == 0) {
    ws[WS_APART + blockIdx.x * 2 + 0] = red[0] + red[2] + red[4] + red[6];
    ws[WS_APART + blockIdx.x * 2 + 1] = red[1] + red[3] + red[5] + red[7];
  }
}

// Reduce 1024 anchor partials + combine with nll sum.
__global__ __launch_bounds__(256) void k_final(
    const float* __restrict__ ws, float* __restrict__ out) {
  __shared__ float red[8];
  int t = threadIdx.x, lane = t & 63, w = t >> 6;
  float a = 0.0f, c = 0.0f;
  for (int i = t; i < 1024; i += 256) {
    a += ws[WS_APART + i * 2 + 0];
    c += ws[WS_APART + i * 2 + 1];
  }
#pragma unroll
  for (int off = 32; off > 0; off >>= 1) {
    a += __shfl_xor(a, off);
    c += __shfl_xor(c, off);
  }
  if (lane == 0) { red[w * 2] = a; red[w * 2 + 1] = c; }
  __syncthreads();
  if (t == 0) {
    float at = red[0] + red[2] + red[4] + red[6];
    float ct = red[1] + red[3] + red[5] + red[7];
    out[0] = at / ct + 10.0f * ws[WS_NLL] * (1.0f / (float)BN_);
  }
}

extern "C" void kernel_launch(void* const* d_in, const int* in_sizes, int n_in,
                              void* d_out, int out_size, void* d_ws, size_t ws_size,
                              hipStream_t stream) {
  const float* emb    = (const float*)d_in[0];
  const float* contr  = (const float*)d_in[1];
  const float* absc   = (const float*)d_in[2];
  const int*   mask   = (const int*)d_in[3];
  const int*   labels = (const int*)d_in[4];
  float* ws  = (float*)d_ws;
  float* out = (float*)d_out;

  k_prep<<<2048, 256, 0, stream>>>(emb, absc, contr, ws);
  k_cluster<<<B_ * K_, 256, 0, stream>>>(contr, labels, ws);
  k_logits_nll<<<256, 128, 0, stream>>>(contr, labels, ws);
  k_anchor<<<1024, 256, 0, stream>>>(mask, ws);
  k_final<<<1, 256, 0, stream>>>(ws, out);
}